// Round 9
// baseline (194.571 us; speedup 1.0000x reference)
//
#include <hip/hip_runtime.h>

// Problem constants
#define B_   4
#define L_   4096
#define DM_  1024
#define DK_  128
#define NSPLIT 4            // KV splits: grid (64,4,4)=1024 blocks
#define OUT_K_OFF 2097152   // B*L*DK
#define OUT_V_OFF 4194304   // 2*B*L*DK

typedef __attribute__((ext_vector_type(4))) float f32x4;
typedef __attribute__((ext_vector_type(8))) short short8;

__device__ __forceinline__ unsigned short f2bf(float f) {
  union { float f; unsigned int u; } v; v.f = f;
  unsigned int u = v.u;
  u += 0x7FFFu + ((u >> 16) & 1u);   // RNE
  return (unsigned short)(u >> 16);
}
__device__ __forceinline__ float bf2f(unsigned short u) {
  union { unsigned int i; float f; } v; v.i = ((unsigned int)u) << 16; return v.f;
}
// packed RNE convert: (lo,hi) -> u32 of 2 bf16 (lo in low 16)
__device__ __forceinline__ unsigned int cvt_pk_bf16(float lo, float hi) {
  unsigned int r;
  asm("v_cvt_pk_bf16_f32 %0, %1, %2" : "=v"(r) : "v"(lo), "v"(hi));
  return r;
}

// async global->LDS, 16B per lane. LDS dest = wave-uniform base (+lane*16 HW).
#define ASYNC16(gsrc, ldst)                                                          \
  __builtin_amdgcn_global_load_lds(                                                  \
      (const __attribute__((address_space(1))) unsigned int*)(gsrc),                 \
      (__attribute__((address_space(3))) unsigned int*)(ldst), 16, 0, 0)

#define MFMA16(a, b, c) __builtin_amdgcn_mfma_f32_16x16x32_bf16((a), (b), (c), 0, 0, 0)
#define VMCNT0() asm volatile("s_waitcnt vmcnt(0)" ::: "memory")
#define VMCNT4() asm volatile("s_waitcnt vmcnt(4)" ::: "memory")

// ---------------------------------------------------------------------------
// Kernel 0: fused fp32 -> bf16 convert of x and the 3 weight matrices.
// grid = 8192 (x) + 3*64 (weights) = 8384 blocks.
// ---------------------------------------------------------------------------
__global__ __launch_bounds__(256) void cvt_all_kernel(
    const float* __restrict__ x, const float* __restrict__ Wq,
    const float* __restrict__ Wk, const float* __restrict__ Wv,
    unsigned short* __restrict__ xb, unsigned short* __restrict__ wb) {
  const int bid = blockIdx.x;
  const float* s;
  unsigned short* d;
  int i;
  if (bid < 8192) {
    s = x; d = xb; i = bid * 256 + threadIdx.x;
  } else {
    int wsel = (bid - 8192) >> 6;          // 64 blocks per weight
    s = (wsel == 0) ? Wq : (wsel == 1) ? Wk : Wv;
    d = wb + (size_t)wsel * (DK_ * DM_);
    i = ((bid - 8192) & 63) * 256 + threadIdx.x;
  }
  const f32x4* p = (const f32x4*)(s + (size_t)i * 8);
  f32x4 a = p[0], b = p[1];
  short8 r;
  r[0] = (short)f2bf(a[0]); r[1] = (short)f2bf(a[1]);
  r[2] = (short)f2bf(a[2]); r[3] = (short)f2bf(a[3]);
  r[4] = (short)f2bf(b[0]); r[5] = (short)f2bf(b[1]);
  r[6] = (short)f2bf(b[2]); r[7] = (short)f2bf(b[3]);
  *(short8*)(d + (size_t)i * 8) = r;
}

// ---------------------------------------------------------------------------
// Kernel 1: projection GEMM, 64-row tiles, 2-phase double-buffered staging.
// grid = (256 m-tiles, 3 weights). (unchanged — measured fine)
// ---------------------------------------------------------------------------
__global__ __launch_bounds__(256) void proj_kernel(
    const unsigned short* __restrict__ xb,   // [B*L][1024] bf16
    const unsigned short* __restrict__ wb,   // [3][128][1024] bf16
    const float* __restrict__ bias_q, const float* __restrict__ bias_k,
    const float* __restrict__ bias_v,
    unsigned short* __restrict__ qb,         // [B*L][128] bf16
    unsigned short* __restrict__ kb,         // [B*L][128] bf16
    unsigned short* __restrict__ vt,         // [B][128][L] bf16 (V transposed)
    float* __restrict__ out) {
  __shared__ __align__(16) char smem[49152];  // 2 x (A 8KB | B 16KB); T reuse 18KB

  const int tid  = threadIdx.x;
  const int w    = tid >> 6;
  const int lane = tid & 63;
  const int lo4  = lane & 15, hi4 = lane >> 4;
  const int wm   = w >> 1, wn = w & 1;        // wave -> 32x64 quadrant
  const int mt   = blockIdx.x;   // 0..255
  const int wt   = blockIdx.y;   // 0..2
  const int r0   = mt * 64;
  const unsigned short* wsrc = wb + (size_t)wt * (DK_ * DM_);

  auto stage = [&](int buf, int kt) {
    const int kc0 = kt * 64;
    char* Al = smem + buf * 24576;
    char* Bl = Al + 8192;
#pragma unroll
    for (int j = 0; j < 2; ++j) {
      unsigned int o   = (unsigned)(w * 2048 + j * 1024 + lane * 16);
      unsigned int row = o >> 7;
      unsigned int cl  = ((o >> 4) & 7) ^ (row & 7);
      ASYNC16(xb + ((size_t)(r0 + row) * DM_ + kc0 + cl * 8), Al + w * 2048 + j * 1024);
    }
#pragma unroll
    for (int j = 0; j < 4; ++j) {
      unsigned int o   = (unsigned)(w * 4096 + j * 1024 + lane * 16);
      unsigned int row = o >> 7;
      unsigned int cl  = ((o >> 4) & 7) ^ (row & 7);
      ASYNC16(wsrc + ((size_t)row * DM_ + kc0 + cl * 8), Bl + w * 4096 + j * 1024);
    }
  };

  f32x4 acc[2][4];
#pragma unroll
  for (int i = 0; i < 2; i++)
#pragma unroll
    for (int j = 0; j < 4; j++) acc[i][j] = (f32x4){0.f, 0.f, 0.f, 0.f};

  stage(0, 0);
  VMCNT0();
  __builtin_amdgcn_s_barrier();
  int cur = 0;

  for (int kt = 0; kt < 16; ++kt) {
    if (kt < 15) stage(cur ^ 1, kt + 1);
    char* Alds = smem + cur * 24576;
    char* Blds = Alds + 8192;
#pragma unroll
    for (int kk = 0; kk < 2; ++kk) {
      short8 af[2], bf[4];
#pragma unroll
      for (int mi = 0; mi < 2; mi++) {
        int row = wm * 32 + mi * 16 + lo4;
        int c   = kk * 4 + hi4;
        af[mi]  = *(const short8*)(Alds + row * 128 + (((c ^ (row & 7))) << 4));
      }
#pragma unroll
      for (int ni = 0; ni < 4; ni++) {
        int col = wn * 64 + ni * 16 + lo4;
        int c   = kk * 4 + hi4;
        bf[ni]  = *(const short8*)(Blds + col * 128 + (((c ^ (col & 7))) << 4));
      }
#pragma unroll
      for (int mi = 0; mi < 2; mi++)
#pragma unroll
        for (int ni = 0; ni < 4; ni++)
          acc[mi][ni] = MFMA16(af[mi], bf[ni], acc[mi][ni]);
    }
    VMCNT0();
    __builtin_amdgcn_s_barrier();
    cur ^= 1;
  }

  const float* bias = (wt == 0) ? bias_q : (wt == 1) ? bias_k : bias_v;
  float bv4[4];
#pragma unroll
  for (int ni = 0; ni < 4; ni++) bv4[ni] = bias[wn * 64 + ni * 16 + lo4];

  const int b_idx = r0 >> 12;      // batch
  const int l0    = r0 & 4095;     // l within batch

  if (wt != 2) {
    unsigned short* dstb = (wt == 0) ? qb : kb;
#pragma unroll
    for (int mi = 0; mi < 2; mi++)
#pragma unroll
      for (int ni = 0; ni < 4; ni++)
#pragma unroll
        for (int reg = 0; reg < 4; reg++) {
          int r   = wm * 32 + mi * 16 + hi4 * 4 + reg;
          int c   = wn * 64 + ni * 16 + lo4;
          float v = acc[mi][ni][reg] + bv4[ni];
          dstb[(size_t)(r0 + r) * DK_ + c] = f2bf(v);
          if (wt == 1) out[OUT_K_OFF + (size_t)(r0 + r) * DK_ + c] = v;
        }
  } else {
    // V: fp32 to out, then LDS transpose -> vt (bf16, [d][l])
    char* T = smem;  // [128 d][144 bytes] (64 l bf16 + 16B pad)
#pragma unroll
    for (int mi = 0; mi < 2; mi++)
#pragma unroll
      for (int ni = 0; ni < 4; ni++)
#pragma unroll
        for (int reg = 0; reg < 4; reg++) {
          int r   = wm * 32 + mi * 16 + hi4 * 4 + reg;
          int c   = wn * 64 + ni * 16 + lo4;
          float v = acc[mi][ni][reg] + bv4[ni];
          out[OUT_V_OFF + (size_t)(r0 + r) * DK_ + c] = v;
          *(unsigned short*)(T + c * 144 + r * 2) = f2bf(v);
        }
    __syncthreads();
#pragma unroll
    for (int i = 0; i < 4; ++i) {
      int q = tid + i * 256;          // 0..1023
      int d = q >> 3, lg = q & 7;
      short8 s8 = *(const short8*)(T + d * 144 + lg * 16);
      *(short8*)(vt + ((size_t)(b_idx * DK_ + d) * L_ + l0 + lg * 8)) = s8;
    }
  }
}

// ---------------------------------------------------------------------------
// Kernel 2: flash attention, KVBLK=32, K+V TRIPLE-buffered, prefetch depth 2
// with counted vmcnt(4) (T3/T4): tile t computes while t+1 and t+2 loads are
// in flight; only t+1's 4 loads are waited per tile. Swapped QK^T + cvt_pk P
// path + static-reference softmax (exact, shift-invariant). LDS 53KB ->
// 3 blocks/CU. grid (64, B, NSPLIT=4) = 1024 blocks.
// ---------------------------------------------------------------------------
__global__ __launch_bounds__(256, 3) void attn_kernel(
    const unsigned short* __restrict__ qb, const unsigned short* __restrict__ kb,
    const unsigned short* __restrict__ vt,
    unsigned short* __restrict__ Opart,   // [NSPLIT][B*L][128] bf16
    float* __restrict__ ml) {             // [NSPLIT][B*L][2] f32
  // K0..K2 @0,8K,16K | V0..V2 @24K,32K,40K | P @49152 (4 waves x 16r x 80B)
  __shared__ __align__(16) char smem[54272];

  const int tid  = threadIdx.x;
  const int w    = tid >> 6;
  const int lane = tid & 63;
  const int lo4  = lane & 15, hi4 = lane >> 4;
  char* Plds = smem + 49152 + w * 1280;   // [16 q][32 l] bf16, 80B pitch

  const int qt = blockIdx.x;  // 0..63
  const int b  = blockIdx.y;  // 0..3
  const int sp = blockIdx.z;  // 0..3
  const int tlo = sp * 32, thi = tlo + 32;   // 32 tiles of 32 keys

  // staging geometry (chunk c = i*256 + w*64 + lane; inverse-swizzled source)
  unsigned int kkey[2], koff[2], vd_[2], voff[2];
#pragma unroll
  for (int i = 0; i < 2; ++i) {
    unsigned int c = i * 256 + w * 64 + lane;
    unsigned int key = c >> 4, cs = c & 15;
    kkey[i] = key;                      // K tile row (0..31), 256B rows
    koff[i] = (cs ^ (key & 7)) * 8;     // element offset in row
    unsigned int d = c >> 2, c2 = c & 3;
    vd_[i]  = d;                        // V^T row d (0..127), 64B rows
    voff[i] = (c2 ^ ((d >> 1) & 3)) * 8;
  }
  const unsigned short* kbase = kb + (size_t)b * L_ * DK_;
  const unsigned short* vbase = vt + (size_t)b * DK_ * L_;

  // per-lane LDS read offsets (constant across tiles)
  unsigned int kaddr[2][4];
#pragma unroll
  for (int st = 0; st < 2; st++) {
    unsigned int key = st * 16 + lo4;
#pragma unroll
    for (int kc = 0; kc < 4; kc++) {
      unsigned int cc = kc * 4 + hi4;
      kaddr[st][kc] = key * 256 + ((cc ^ (key & 7)) << 4);
    }
  }
  unsigned int vaddr[8];
#pragma unroll
  for (int dt = 0; dt < 8; dt++) {
    unsigned int d = dt * 16 + lo4;
    vaddr[dt] = d * 64 + ((hi4 ^ ((d >> 1) & 3)) << 4);
  }

  auto stage = [&](int buf, int t) {
    char* Kd = smem + buf * 8192;
    char* Vd = smem + 24576 + buf * 8192;
#pragma unroll
    for (int i = 0; i < 2; ++i) {
      ASYNC16(kbase + ((size_t)(t * 32 + kkey[i]) * DK_ + koff[i]),
              Kd + i * 4096 + w * 1024);
      ASYNC16(vbase + ((size_t)vd_[i] * L_ + t * 32 + voff[i]),
              Vd + i * 4096 + w * 1024);
    }
  };

  // Q fragments (16 rows x 128 d) in registers for the whole kernel.
  // Same registers serve as the B-operand of the swapped QK^T (col=lo4=q).
  short8 aq[4];
  {
    const unsigned short* qp =
        qb + ((size_t)(b * L_ + qt * 64 + w * 16 + lo4) * DK_ + hi4 * 8);
#pragma unroll
    for (int kc = 0; kc < 4; kc++) aq[kc] = *(const short8*)(qp + kc * 32);
  }

  f32x4 o_acc[8];
#pragma unroll
  for (int dt = 0; dt < 8; dt++) o_acc[dt] = (f32x4){0.f, 0.f, 0.f, 0.f};
  float ls = 0.f;   // sum of P for q = lo4 (this lane's row)
  const float SC = 0.08838834764831845f * 1.4426950408889634f;  // 1/sqrt(128)*log2(e)

  // prologue: prefetch 2 tiles deep
  stage(0, tlo);
  stage(1, tlo + 1);
  VMCNT4();                       // buf0 landed (buf1's 4 still in flight)
  __builtin_amdgcn_s_barrier();
  int cb = 0;                     // compute buffer

  for (int t = tlo; t < thi; ++t) {
    const bool pf = (t + 2 < thi);
    if (pf) {
      int sb = cb + 2; if (sb >= 3) sb -= 3;
      stage(sb, t + 2);
    }
    const char* Kl = smem + cb * 8192;
    const char* Vl = smem + 24576 + cb * 8192;

    // S^T = K Q^T : s[st][reg] = S[key = st*16 + hi4*4 + reg][q = lo4]
    f32x4 s0 = (f32x4){0.f, 0.f, 0.f, 0.f};
    f32x4 s1 = (f32x4){0.f, 0.f, 0.f, 0.f};
#pragma unroll
    for (int kc = 0; kc < 4; kc++) {
      s0 = MFMA16(*(const short8*)(Kl + kaddr[0][kc]), aq[kc], s0);
      s1 = MFMA16(*(const short8*)(Kl + kaddr[1][kc]), aq[kc], s1);
    }

    // static-reference softmax: p = 2^(s*SC - 16); all 8 values same q row
    float p[8];
#pragma unroll
    for (int reg = 0; reg < 4; reg++) {
      p[reg]     = exp2f(fmaf(s0[reg], SC, -16.f));
      p[4 + reg] = exp2f(fmaf(s1[reg], SC, -16.f));
    }
    ls += ((p[0] + p[1]) + (p[2] + p[3])) + ((p[4] + p[5]) + (p[6] + p[7]));

    // pack to bf16 pairs, store P[q=lo4][keys] (2 x ds_write_b64, 80B pitch)
    {
      uint2 w0, w1;
      w0.x = cvt_pk_bf16(p[0], p[1]);  w0.y = cvt_pk_bf16(p[2], p[3]);
      w1.x = cvt_pk_bf16(p[4], p[5]);  w1.y = cvt_pk_bf16(p[6], p[7]);
      *(uint2*)(Plds + lo4 * 80 + hi4 * 8)      = w0;
      *(uint2*)(Plds + lo4 * 80 + 32 + hi4 * 8) = w1;
    }

    // O += P @ V : A-frag = P[q=lo4][l = hi4*8..+7] (intra-wave, lgkm only)
    {
      short8 pa = *(const short8*)(Plds + lo4 * 80 + hi4 * 16);
#pragma unroll
      for (int dt = 0; dt < 8; dt++)
        o_acc[dt] = MFMA16(pa, *(const short8*)(Vl + vaddr[dt]), o_acc[dt]);
    }

    // counted wait: only tile t+1's 4 loads must land before the barrier
    if (pf)                 { VMCNT4(); }
    else if (t + 1 < thi)   { VMCNT0(); }
    __builtin_amdgcn_s_barrier();
    cb = (cb == 2) ? 0 : cb + 1;
  }

  // epilogue: reduce ls across the 4 hi4-lanes (q = lo4 complete sum)
  ls += __shfl_xor(ls, 16);
  ls += __shfl_xor(ls, 32);
  const size_t rowbase = (size_t)(sp * B_ + b) * L_ + qt * 64 + w * 16;
  if (hi4 == 0) {
    size_t idx = rowbase + lo4;
    ml[idx * 2 + 0] = 16.0f;        // constant reference -> combine wgt = 1
    ml[idx * 2 + 1] = ls;
  }
#pragma unroll
  for (int dt = 0; dt < 8; dt++)
#pragma unroll
    for (int reg = 0; reg < 4; reg++)
      Opart[(rowbase + hi4 * 4 + reg) * 128 + dt * 16 + lo4] = f2bf(o_acc[dt][reg]);
}

// ---------------------------------------------------------------------------
// Kernel 3: combine the NSPLIT partials.
// ---------------------------------------------------------------------------
__global__ __launch_bounds__(256) void combine_kernel(
    const unsigned short* __restrict__ Opart, const float* __restrict__ ml,
    float* __restrict__ out) {
  const int qt = blockIdx.x, b = blockIdx.y, tid = threadIdx.x;
#pragma unroll
  for (int i = 0; i < 4; ++i) {
    int idx = i * 256 + tid;          // 0..1023
    int row = idx >> 4, cg = idx & 15;
    size_t grow = (size_t)b * L_ + qt * 64 + row;
    float ms[NSPLIT], lv[NSPLIT], M = -__builtin_inff();
#pragma unroll
    for (int s = 0; s < NSPLIT; s++) {
      size_t p = ((size_t)s * B_ * L_ + grow) * 2;
      ms[s] = ml[p]; lv[s] = ml[p + 1];
      M = fmaxf(M, ms[s]);
    }
    float acc[8] = {0.f, 0.f, 0.f, 0.f, 0.f, 0.f, 0.f, 0.f};
    float lsum = 0.f;
#pragma unroll
    for (int s = 0; s < NSPLIT; s++) {
      float wgt = exp2f(ms[s] - M);
      lsum += lv[s] * wgt;
      short8 v = *(const short8*)&Opart[((size_t)(s * B_ + b) * L_ + qt * 64 + row) * 128 + cg * 8];
#pragma unroll
      for (int j = 0; j < 8; j++) acc[j] += bf2f((unsigned short)v[j]) * wgt;
    }
    float sc = 4.0f / lsum;   // NUM_BLOCKS / denom
    f32x4 o0 = {acc[0] * sc, acc[1] * sc, acc[2] * sc, acc[3] * sc};
    f32x4 o1 = {acc[4] * sc, acc[5] * sc, acc[6] * sc, acc[7] * sc};
    float* dst = out + grow * 128 + cg * 8;
    *(f32x4*)dst = o0;
    *(f32x4*)(dst + 4) = o1;
  }
}

// ---------------------------------------------------------------------------
extern "C" void kernel_launch(void* const* d_in, const int* in_sizes, int n_in,
                              void* d_out, int out_size, void* d_ws, size_t ws_size,
                              hipStream_t stream) {
  const float* x  = (const float*)d_in[0];
  const float* Wq = (const float*)d_in[1];
  const float* bq = (const float*)d_in[2];
  const float* Wk = (const float*)d_in[3];
  const float* bk = (const float*)d_in[4];
  const float* Wv = (const float*)d_in[5];
  const float* bv = (const float*)d_in[6];
  float* out = (float*)d_out;

  // workspace: xb | wb | qb | kb | vt ; xb region reused for attn partials
  unsigned short* xb = (unsigned short*)d_ws;
  unsigned short* wb = xb + (size_t)B_ * L_ * DM_;
  unsigned short* qb = wb + (size_t)3 * DK_ * DM_;
  unsigned short* kb = qb + (size_t)B_ * L_ * DK_;
  unsigned short* vt = kb + (size_t)B_ * L_ * DK_;
  unsigned short* Opart = xb;                                   // [NSPLIT][B*L][128] bf16
  float* ml = (float*)(xb + (size_t)NSPLIT * B_ * L_ * DK_);    // [NSPLIT][B*L][2] f32

  cvt_all_kernel<<<8192 + 192, 256, 0, stream>>>(x, Wq, Wk, Wv, xb, wb);
  proj_kernel<<<dim3(256, 3), 256, 0, stream>>>(xb, wb, bq, bk, bv, qb, kb, vt, out);
  attn_kernel<<<dim3(64, B_, NSPLIT), 256, 0, stream>>>(qb, kb, vt, Opart, ml);
  combine_kernel<<<dim3(64, B_), 256, 0, stream>>>(Opart, ml, out);
}

// Round 10
// 184.120 us; speedup vs baseline: 1.0568x; 1.0568x over previous
//
#include <hip/hip_runtime.h>

// Problem constants
#define B_   4
#define L_   4096
#define DM_  1024
#define DK_  128
#define NSPLIT 4            // KV splits: grid (64,4,4)=1024 blocks = 4/CU
#define OUT_K_OFF 2097152   // B*L*DK
#define OUT_V_OFF 4194304   // 2*B*L*DK

typedef __attribute__((ext_vector_type(4))) float f32x4;
typedef __attribute__((ext_vector_type(8))) short short8;

__device__ __forceinline__ unsigned short f2bf(float f) {
  union { float f; unsigned int u; } v; v.f = f;
  unsigned int u = v.u;
  u += 0x7FFFu + ((u >> 16) & 1u);   // RNE
  return (unsigned short)(u >> 16);
}
__device__ __forceinline__ float bf2f(unsigned short u) {
  union { unsigned int i; float f; } v; v.i = ((unsigned int)u) << 16; return v.f;
}
// packed RNE convert: (lo,hi) -> u32 of 2 bf16 (lo in low 16)
__device__ __forceinline__ unsigned int cvt_pk_bf16(float lo, float hi) {
  unsigned int r;
  asm("v_cvt_pk_bf16_f32 %0, %1, %2" : "=v"(r) : "v"(lo), "v"(hi));
  return r;
}

// async global->LDS, 16B per lane. LDS dest = wave-uniform base (+lane*16 HW).
#define ASYNC16(gsrc, ldst)                                                          \
  __builtin_amdgcn_global_load_lds(                                                  \
      (const __attribute__((address_space(1))) unsigned int*)(gsrc),                 \
      (__attribute__((address_space(3))) unsigned int*)(ldst), 16, 0, 0)

#define MFMA16(a, b, c) __builtin_amdgcn_mfma_f32_16x16x32_bf16((a), (b), (c), 0, 0, 0)
#define VMCNT0() asm volatile("s_waitcnt vmcnt(0)" ::: "memory")

// ---------------------------------------------------------------------------
// Kernel 0: fused fp32 -> bf16 convert of x and the 3 weight matrices.
// grid = 8192 (x) + 3*64 (weights) = 8384 blocks.
// ---------------------------------------------------------------------------
__global__ __launch_bounds__(256) void cvt_all_kernel(
    const float* __restrict__ x, const float* __restrict__ Wq,
    const float* __restrict__ Wk, const float* __restrict__ Wv,
    unsigned short* __restrict__ xb, unsigned short* __restrict__ wb) {
  const int bid = blockIdx.x;
  const float* s;
  unsigned short* d;
  int i;
  if (bid < 8192) {
    s = x; d = xb; i = bid * 256 + threadIdx.x;
  } else {
    int wsel = (bid - 8192) >> 6;          // 64 blocks per weight
    s = (wsel == 0) ? Wq : (wsel == 1) ? Wk : Wv;
    d = wb + (size_t)wsel * (DK_ * DM_);
    i = ((bid - 8192) & 63) * 256 + threadIdx.x;
  }
  const f32x4* p = (const f32x4*)(s + (size_t)i * 8);
  f32x4 a = p[0], b = p[1];
  short8 r;
  r[0] = (short)f2bf(a[0]); r[1] = (short)f2bf(a[1]);
  r[2] = (short)f2bf(a[2]); r[3] = (short)f2bf(a[3]);
  r[4] = (short)f2bf(b[0]); r[5] = (short)f2bf(b[1]);
  r[6] = (short)f2bf(b[2]); r[7] = (short)f2bf(b[3]);
  *(short8*)(d + (size_t)i * 8) = r;
}

// ---------------------------------------------------------------------------
// Kernel 1: projection GEMM, 64-row tiles, 2-phase double-buffered staging.
// grid = (256 m-tiles, 3 weights). (unchanged — measured fine)
// ---------------------------------------------------------------------------
__global__ __launch_bounds__(256) void proj_kernel(
    const unsigned short* __restrict__ xb,   // [B*L][1024] bf16
    const unsigned short* __restrict__ wb,   // [3][128][1024] bf16
    const float* __restrict__ bias_q, const float* __restrict__ bias_k,
    const float* __restrict__ bias_v,
    unsigned short* __restrict__ qb,         // [B*L][128] bf16
    unsigned short* __restrict__ kb,         // [B*L][128] bf16
    unsigned short* __restrict__ vt,         // [B][128][L] bf16 (V transposed)
    float* __restrict__ out) {
  __shared__ __align__(16) char smem[49152];  // 2 x (A 8KB | B 16KB); T reuse 18KB

  const int tid  = threadIdx.x;
  const int w    = tid >> 6;
  const int lane = tid & 63;
  const int lo4  = lane & 15, hi4 = lane >> 4;
  const int wm   = w >> 1, wn = w & 1;        // wave -> 32x64 quadrant
  const int mt   = blockIdx.x;   // 0..255
  const int wt   = blockIdx.y;   // 0..2
  const int r0   = mt * 64;
  const unsigned short* wsrc = wb + (size_t)wt * (DK_ * DM_);

  auto stage = [&](int buf, int kt) {
    const int kc0 = kt * 64;
    char* Al = smem + buf * 24576;
    char* Bl = Al + 8192;
#pragma unroll
    for (int j = 0; j < 2; ++j) {
      unsigned int o   = (unsigned)(w * 2048 + j * 1024 + lane * 16);
      unsigned int row = o >> 7;
      unsigned int cl  = ((o >> 4) & 7) ^ (row & 7);
      ASYNC16(xb + ((size_t)(r0 + row) * DM_ + kc0 + cl * 8), Al + w * 2048 + j * 1024);
    }
#pragma unroll
    for (int j = 0; j < 4; ++j) {
      unsigned int o   = (unsigned)(w * 4096 + j * 1024 + lane * 16);
      unsigned int row = o >> 7;
      unsigned int cl  = ((o >> 4) & 7) ^ (row & 7);
      ASYNC16(wsrc + ((size_t)row * DM_ + kc0 + cl * 8), Bl + w * 4096 + j * 1024);
    }
  };

  f32x4 acc[2][4];
#pragma unroll
  for (int i = 0; i < 2; i++)
#pragma unroll
    for (int j = 0; j < 4; j++) acc[i][j] = (f32x4){0.f, 0.f, 0.f, 0.f};

  stage(0, 0);
  VMCNT0();
  __builtin_amdgcn_s_barrier();
  int cur = 0;

  for (int kt = 0; kt < 16; ++kt) {
    if (kt < 15) stage(cur ^ 1, kt + 1);
    char* Alds = smem + cur * 24576;
    char* Blds = Alds + 8192;
#pragma unroll
    for (int kk = 0; kk < 2; ++kk) {
      short8 af[2], bf[4];
#pragma unroll
      for (int mi = 0; mi < 2; mi++) {
        int row = wm * 32 + mi * 16 + lo4;
        int c   = kk * 4 + hi4;
        af[mi]  = *(const short8*)(Alds + row * 128 + (((c ^ (row & 7))) << 4));
      }
#pragma unroll
      for (int ni = 0; ni < 4; ni++) {
        int col = wn * 64 + ni * 16 + lo4;
        int c   = kk * 4 + hi4;
        bf[ni]  = *(const short8*)(Blds + col * 128 + (((c ^ (col & 7))) << 4));
      }
#pragma unroll
      for (int mi = 0; mi < 2; mi++)
#pragma unroll
        for (int ni = 0; ni < 4; ni++)
          acc[mi][ni] = MFMA16(af[mi], bf[ni], acc[mi][ni]);
    }
    VMCNT0();
    __builtin_amdgcn_s_barrier();
    cur ^= 1;
  }

  const float* bias = (wt == 0) ? bias_q : (wt == 1) ? bias_k : bias_v;
  float bv4[4];
#pragma unroll
  for (int ni = 0; ni < 4; ni++) bv4[ni] = bias[wn * 64 + ni * 16 + lo4];

  const int b_idx = r0 >> 12;      // batch
  const int l0    = r0 & 4095;     // l within batch

  if (wt != 2) {
    unsigned short* dstb = (wt == 0) ? qb : kb;
#pragma unroll
    for (int mi = 0; mi < 2; mi++)
#pragma unroll
      for (int ni = 0; ni < 4; ni++)
#pragma unroll
        for (int reg = 0; reg < 4; reg++) {
          int r   = wm * 32 + mi * 16 + hi4 * 4 + reg;
          int c   = wn * 64 + ni * 16 + lo4;
          float v = acc[mi][ni][reg] + bv4[ni];
          dstb[(size_t)(r0 + r) * DK_ + c] = f2bf(v);
          if (wt == 1) out[OUT_K_OFF + (size_t)(r0 + r) * DK_ + c] = v;
        }
  } else {
    // V: fp32 to out, then LDS transpose -> vt (bf16, [d][l])
    char* T = smem;  // [128 d][144 bytes] (64 l bf16 + 16B pad)
#pragma unroll
    for (int mi = 0; mi < 2; mi++)
#pragma unroll
      for (int ni = 0; ni < 4; ni++)
#pragma unroll
        for (int reg = 0; reg < 4; reg++) {
          int r   = wm * 32 + mi * 16 + hi4 * 4 + reg;
          int c   = wn * 64 + ni * 16 + lo4;
          float v = acc[mi][ni][reg] + bv4[ni];
          out[OUT_V_OFF + (size_t)(r0 + r) * DK_ + c] = v;
          *(unsigned short*)(T + c * 144 + r * 2) = f2bf(v);
        }
    __syncthreads();
#pragma unroll
    for (int i = 0; i < 4; ++i) {
      int q = tid + i * 256;          // 0..1023
      int d = q >> 3, lg = q & 7;
      short8 s8 = *(const short8*)(T + d * 144 + lg * 16);
      *(short8*)(vt + ((size_t)(b_idx * DK_ + d) * L_ + l0 + lg * 8)) = s8;
    }
  }
}

// ---------------------------------------------------------------------------
// Kernel 2: flash attention — R8 structure (KVBLK=32, K+V double-buffered,
// 4 blocks/CU, swapped QK^T, cvt_pk P path, static-reference softmax) plus
// the ones-column MFMA trick: row-sums l accumulate in the matrix pipe
// (ls_acc = mfma(P, ones)) instead of 7 serial VALU adds + epilogue shuffles.
// grid (64, B, NSPLIT=4) = 1024 blocks.
// ---------------------------------------------------------------------------
__global__ __launch_bounds__(256, 4) void attn_kernel(
    const unsigned short* __restrict__ qb, const unsigned short* __restrict__ kb,
    const unsigned short* __restrict__ vt,
    unsigned short* __restrict__ Opart,   // [NSPLIT][B*L][128] bf16
    float* __restrict__ ml) {             // [NSPLIT][B*L][2] f32
  // K0 @0 | K1 @8192 | V0 @16384 | V1 @24576 | P @32768 (4 waves x 16r x 80B)
  __shared__ __align__(16) char smem[37888];

  const int tid  = threadIdx.x;
  const int w    = tid >> 6;
  const int lane = tid & 63;
  const int lo4  = lane & 15, hi4 = lane >> 4;
  char* Plds = smem + 32768 + w * 1280;   // [16 q][32 l] bf16, 80B pitch

  const int qt = blockIdx.x;  // 0..63
  const int b  = blockIdx.y;  // 0..3
  const int sp = blockIdx.z;  // 0..3
  const int tlo = sp * 32, thi = tlo + 32;   // 32 tiles of 32 keys

  // staging geometry (chunk c = i*256 + w*64 + lane; inverse-swizzled source)
  unsigned int kkey[2], koff[2], vd_[2], voff[2];
#pragma unroll
  for (int i = 0; i < 2; ++i) {
    unsigned int c = i * 256 + w * 64 + lane;
    unsigned int key = c >> 4, cs = c & 15;
    kkey[i] = key;                      // K tile row (0..31), 256B rows
    koff[i] = (cs ^ (key & 7)) * 8;     // element offset in row
    unsigned int d = c >> 2, c2 = c & 3;
    vd_[i]  = d;                        // V^T row d (0..127), 64B rows
    voff[i] = (c2 ^ ((d >> 1) & 3)) * 8;
  }
  const unsigned short* kbase = kb + (size_t)b * L_ * DK_;
  const unsigned short* vbase = vt + (size_t)b * DK_ * L_;

  // per-lane LDS read offsets (constant across tiles)
  unsigned int kaddr[2][4];
#pragma unroll
  for (int st = 0; st < 2; st++) {
    unsigned int key = st * 16 + lo4;
#pragma unroll
    for (int kc = 0; kc < 4; kc++) {
      unsigned int cc = kc * 4 + hi4;
      kaddr[st][kc] = key * 256 + ((cc ^ (key & 7)) << 4);
    }
  }
  unsigned int vaddr[8];
#pragma unroll
  for (int dt = 0; dt < 8; dt++) {
    unsigned int d = dt * 16 + lo4;
    vaddr[dt] = d * 64 + ((hi4 ^ ((d >> 1) & 3)) << 4);
  }

  auto stage = [&](int buf, int t) {
    char* Kd = smem + buf * 8192;
    char* Vd = smem + 16384 + buf * 8192;
#pragma unroll
    for (int i = 0; i < 2; ++i) {
      ASYNC16(kbase + ((size_t)(t * 32 + kkey[i]) * DK_ + koff[i]),
              Kd + i * 4096 + w * 1024);
      ASYNC16(vbase + ((size_t)vd_[i] * L_ + t * 32 + voff[i]),
              Vd + i * 4096 + w * 1024);
    }
  };

  // Q fragments (16 rows x 128 d) in registers for the whole kernel.
  short8 aq[4];
  {
    const unsigned short* qp =
        qb + ((size_t)(b * L_ + qt * 64 + w * 16 + lo4) * DK_ + hi4 * 8);
#pragma unroll
    for (int kc = 0; kc < 4; kc++) aq[kc] = *(const short8*)(qp + kc * 32);
  }

  // ones B-fragment (bf16 1.0 = 0x3F80) for the row-sum MFMA
  short8 ones;
#pragma unroll
  for (int j = 0; j < 8; j++) ones[j] = (short)0x3F80;

  f32x4 o_acc[8];
#pragma unroll
  for (int dt = 0; dt < 8; dt++) o_acc[dt] = (f32x4){0.f, 0.f, 0.f, 0.f};
  f32x4 ls_acc = (f32x4){0.f, 0.f, 0.f, 0.f};  // row-sums, q = hi4*4+reg
  const float SC = 0.08838834764831845f * 1.4426950408889634f;  // 1/sqrt(128)*log2(e)

  stage(0, tlo);
  VMCNT0();
  __builtin_amdgcn_s_barrier();
  int cur = 0;

  for (int t = tlo; t < thi; ++t) {
    if (t + 1 < thi) stage(cur ^ 1, t + 1);   // prefetch next K+V tile
    const char* Kl = smem + cur * 8192;
    const char* Vl = smem + 16384 + cur * 8192;

    // S^T = K Q^T : s[st][reg] = S[key = st*16 + hi4*4 + reg][q = lo4]
    f32x4 s0 = (f32x4){0.f, 0.f, 0.f, 0.f};
    f32x4 s1 = (f32x4){0.f, 0.f, 0.f, 0.f};
#pragma unroll
    for (int kc = 0; kc < 4; kc++) {
      s0 = MFMA16(*(const short8*)(Kl + kaddr[0][kc]), aq[kc], s0);
      s1 = MFMA16(*(const short8*)(Kl + kaddr[1][kc]), aq[kc], s1);
    }

    // static-reference softmax: p = 2^(s*SC - 16); exact (shift-invariant)
    float p[8];
#pragma unroll
    for (int reg = 0; reg < 4; reg++) {
      p[reg]     = exp2f(fmaf(s0[reg], SC, -16.f));
      p[4 + reg] = exp2f(fmaf(s1[reg], SC, -16.f));
    }

    // pack to bf16 pairs, store P[q=lo4][keys] (2 x ds_write_b64, 80B pitch)
    {
      uint2 w0, w1;
      w0.x = cvt_pk_bf16(p[0], p[1]);  w0.y = cvt_pk_bf16(p[2], p[3]);
      w1.x = cvt_pk_bf16(p[4], p[5]);  w1.y = cvt_pk_bf16(p[6], p[7]);
      *(uint2*)(Plds + lo4 * 80 + hi4 * 8)      = w0;
      *(uint2*)(Plds + lo4 * 80 + 32 + hi4 * 8) = w1;
    }

    // O += P @ V ; l += P @ 1 (row sums ride the matrix pipe)
    {
      short8 pa = *(const short8*)(Plds + lo4 * 80 + hi4 * 16);
#pragma unroll
      for (int dt = 0; dt < 8; dt++)
        o_acc[dt] = MFMA16(pa, *(const short8*)(Vl + vaddr[dt]), o_acc[dt]);
      ls_acc = MFMA16(pa, ones, ls_acc);
    }

    VMCNT0();                       // prefetch (issued at top) complete
    __builtin_amdgcn_s_barrier();
    cur ^= 1;
  }

  // epilogue: ls_acc[reg] = sum over keys for q = hi4*4+reg (same in all lo4)
  const size_t rowbase = (size_t)(sp * B_ + b) * L_ + qt * 64 + w * 16;
  if (lo4 == 0) {
#pragma unroll
    for (int reg = 0; reg < 4; reg++) {
      size_t idx = rowbase + hi4 * 4 + reg;
      ml[idx * 2 + 0] = 16.0f;      // constant reference -> combine wgt = 1
      ml[idx * 2 + 1] = ls_acc[reg];
    }
  }
#pragma unroll
  for (int dt = 0; dt < 8; dt++)
#pragma unroll
    for (int reg = 0; reg < 4; reg++)
      Opart[(rowbase + hi4 * 4 + reg) * 128 + dt * 16 + lo4] = f2bf(o_acc[dt][reg]);
}

// ---------------------------------------------------------------------------
// Kernel 3: combine the NSPLIT partials.
// ---------------------------------------------------------------------------
__global__ __launch_bounds__(256) void combine_kernel(
    const unsigned short* __restrict__ Opart, const float* __restrict__ ml,
    float* __restrict__ out) {
  const int qt = blockIdx.x, b = blockIdx.y, tid = threadIdx.x;
#pragma unroll
  for (int i = 0; i < 4; ++i) {
    int idx = i * 256 + tid;          // 0..1023
    int row = idx >> 4, cg = idx & 15;
    size_t grow = (size_t)b * L_ + qt * 64 + row;
    float ms[NSPLIT], lv[NSPLIT], M = -__builtin_inff();
#pragma unroll
    for (int s = 0; s < NSPLIT; s++) {
      size_t p = ((size_t)s * B_ * L_ + grow) * 2;
      ms[s] = ml[p]; lv[s] = ml[p + 1];
      M = fmaxf(M, ms[s]);
    }
    float acc[8] = {0.f, 0.f, 0.f, 0.f, 0.f, 0.f, 0.f, 0.f};
    float lsum = 0.f;
#pragma unroll
    for (int s = 0; s < NSPLIT; s++) {
      float wgt = exp2f(ms[s] - M);
      lsum += lv[s] * wgt;
      short8 v = *(const short8*)&Opart[((size_t)(s * B_ + b) * L_ + qt * 64 + row) * 128 + cg * 8];
#pragma unroll
      for (int j = 0; j < 8; j++) acc[j] += bf2f((unsigned short)v[j]) * wgt;
    }
    float sc = 4.0f / lsum;   // NUM_BLOCKS / denom
    f32x4 o0 = {acc[0] * sc, acc[1] * sc, acc[2] * sc, acc[3] * sc};
    f32x4 o1 = {acc[4] * sc, acc[5] * sc, acc[6] * sc, acc[7] * sc};
    float* dst = out + grow * 128 + cg * 8;
    *(f32x4*)dst = o0;
    *(f32x4*)(dst + 4) = o1;
  }
}

// ---------------------------------------------------------------------------
extern "C" void kernel_launch(void* const* d_in, const int* in_sizes, int n_in,
                              void* d_out, int out_size, void* d_ws, size_t ws_size,
                              hipStream_t stream) {
  const float* x  = (const float*)d_in[0];
  const float* Wq = (const float*)d_in[1];
  const float* bq = (const float*)d_in[2];
  const float* Wk = (const float*)d_in[3];
  const float* bk = (const float*)d_in[4];
  const float* Wv = (const float*)d_in[5];
  const float* bv = (const float*)d_in[6];
  float* out = (float*)d_out;

  // workspace: xb | wb | qb | kb | vt ; xb region reused for attn partials
  unsigned short* xb = (unsigned short*)d_ws;
  unsigned short* wb = xb + (size_t)B_ * L_ * DM_;
  unsigned short* qb = wb + (size_t)3 * DK_ * DM_;
  unsigned short* kb = qb + (size_t)B_ * L_ * DK_;
  unsigned short* vt = kb + (size_t)B_ * L_ * DK_;
  unsigned short* Opart = xb;                                   // [NSPLIT][B*L][128] bf16
  float* ml = (float*)(xb + (size_t)NSPLIT * B_ * L_ * DK_);    // [NSPLIT][B*L][2] f32

  cvt_all_kernel<<<8192 + 192, 256, 0, stream>>>(x, Wq, Wk, Wv, xb, wb);
  proj_kernel<<<dim3(256, 3), 256, 0, stream>>>(xb, wb, bq, bk, bv, qb, kb, vt, out);
  attn_kernel<<<dim3(64, B_, NSPLIT), 256, 0, stream>>>(qb, kb, vt, Opart, ml);
  combine_kernel<<<dim3(64, B_), 256, 0, stream>>>(Opart, ml, out);
}